// Round 5
// baseline (233.407 us; speedup 1.0000x reference)
//
#include <hip/hip_runtime.h>
#include <hip/hip_bf16.h>
#include <math.h>

// B=4, N=4096, F=512, C=64. M = B*N = 16384 rows.
#define M_ROWS 16384
#define F_DIM 512
#define C_DIM 64

typedef short bf16x8 __attribute__((ext_vector_type(8)));
typedef float floatx4 __attribute__((ext_vector_type(4)));
typedef unsigned short ushortx8 __attribute__((ext_vector_type(8)));
typedef unsigned short ushortx4 __attribute__((ext_vector_type(4)));

static __device__ __forceinline__ unsigned short f2bf(float x) {
    __hip_bfloat16 h = __float2bfloat16(x);   // RN
    return *reinterpret_cast<unsigned short*>(&h);
}
static __device__ __forceinline__ float bf2f(unsigned short h) {
    unsigned int u = ((unsigned int)h) << 16;
    return __builtin_bit_cast(float, u);
}

// LDS-only barrier: global loads stay in flight (no vmcnt(0) drain).
static __device__ __forceinline__ void lgkm_barrier() {
    asm volatile("s_waitcnt lgkmcnt(0)\n\ts_barrier" ::: "memory");
}

// ---------------------------------------------------------------------------
// Frag-linear layouts (MFMA B-operand order): element (n,k) of a 16-col group
// lives at lane=(k>>3&3)*16+(n&15), j=k&7 -> [group][lane][8] contiguous.
//   wt    : group = (c>>4)*16 + (k>>5)            (640 cols x 512 k)
//   h_sw  : [b][mtile(64)][group=(Fcol>>4)*2+(mloc>>5)][lane][8]
// ---------------------------------------------------------------------------

// Kernel 0: weight transpose + bf16 hi/lo split -> frag-linear.
__global__ __launch_bounds__(64) void prep_w_kernel(
    const float* __restrict__ Wf, const float* __restrict__ Wg,
    const float* __restrict__ Wh,
    unsigned short* __restrict__ wt_hi, unsigned short* __restrict__ wt_lo)
{
    const int c = blockIdx.x;
    const int t = threadIdx.x;
    const float* W; int ld, cl;
    if (c < 64)       { W = Wf; ld = C_DIM; cl = c; }
    else if (c < 128) { W = Wg; ld = C_DIM; cl = c - 64; }
    else              { W = Wh; ld = F_DIM; cl = c - 128; }
    const int ng = c >> 4, l16 = c & 15;
    for (int k = t; k < F_DIM; k += 64) {
        const float x = W[(size_t)k * ld + cl];
        const unsigned short h = f2bf(x);
        const int kh = k >> 5, qd = (k >> 3) & 3, j = k & 7;
        const size_t off = (((size_t)(ng * 16 + kh) * 64) + qd * 16 + l16) * 8 + j;
        wt_hi[off] = h;
        wt_lo[off] = f2bf(x - bf2f(h));
    }
}

// ---------------------------------------------------------------------------
// Kernel 1: MFMA embed GEMM, 64 rows x 128 cols per block. Linear grid of
// 1280 with XCD-aware swizzle: the 5 column-passes (y=0 fg fused, y=1..4 h)
// of one row-tile land on the SAME XCD in ADJACENT dispatch slots, so the
// 128 KB V row-tile is fetched from HBM once and L2-hits 4x (was: grid
// (256,5) dispatched all y=0 first -> V re-read from HBM 5x = 160 MB).
// Decode: xcd = bid&7, s = bid>>3; y = s%5; q = xcd + 8*(s/5).
// ---------------------------------------------------------------------------
#define BM 64
#define LDK 72

__global__ __launch_bounds__(256, 4) void embed_mfma_kernel(
    const float* __restrict__ V,
    const unsigned short* __restrict__ wt_hi, const unsigned short* __restrict__ wt_lo,
    const float* __restrict__ bf, const float* __restrict__ bg,
    const float* __restrict__ bh,
    unsigned short* __restrict__ f_bf, unsigned short* __restrict__ g_bf,
    unsigned short* __restrict__ h_sw)
{
    __shared__ __align__(16) unsigned short a_hi[BM][LDK];
    __shared__ __align__(16) unsigned short a_lo[BM][LDK];

    const int t   = threadIdx.x;
    const int bid = blockIdx.x;
    const int yb  = (bid >> 3) % 5;
    const int q   = (bid & 7) + 8 * ((bid >> 3) / 5);
    const int R0  = q * BM;
    const bool fg = (yb == 0);
    const int cbase = fg ? 0 : yb * 128;   // wt col base (g at 64, h at 128+)

    const int w = t >> 6, lane = t & 63, quad = lane >> 4, l16 = lane & 15;

    floatx4 acc[4][2];
    #pragma unroll
    for (int rt = 0; rt < 4; ++rt)
        #pragma unroll
        for (int c = 0; c < 2; ++c)
            acc[rt][c] = (floatx4){0.f, 0.f, 0.f, 0.f};

    const int arow = t >> 4;          // 0..15 (+16/round)
    const int acol = (t & 15) * 4;    // float index (16 B chunks)
    const int ng0  = (cbase >> 4) + w * 2;

    #pragma unroll 1
    for (int k0 = 0; k0 < F_DIM; k0 += 64) {
        lgkm_barrier();   // protect previous iteration's a-frag reads
        // ---- stage A: V fp32 -> bf16 hi/lo in LDS ----
        #pragma unroll
        for (int rr = 0; rr < 4; ++rr) {
            const int row = rr * 16 + arow;
            const float4 x = *(const float4*)(V + (size_t)(R0 + row) * F_DIM + k0 + acol);
            const float xs[4] = {x.x, x.y, x.z, x.w};
            ushortx4 hi, lo;
            #pragma unroll
            for (int jj = 0; jj < 4; ++jj) {
                const unsigned short hb2 = f2bf(xs[jj]);
                hi[jj] = hb2;
                lo[jj] = f2bf(xs[jj] - bf2f(hb2));
            }
            *(ushortx4*)&a_hi[row][acol] = hi;
            if (fg) *(ushortx4*)&a_lo[row][acol] = lo;
        }
        lgkm_barrier();
        // ---- compute ----
        #pragma unroll
        for (int kk = 0; kk < 2; ++kk) {
            const int kh = (k0 >> 5) + kk;
            const bf16x8 b0 = *(const bf16x8*)(wt_hi + (((size_t)(ng0 * 16 + kh)) * 64 + lane) * 8);
            const bf16x8 b1 = *(const bf16x8*)(wt_hi + (((size_t)((ng0 + 1) * 16 + kh)) * 64 + lane) * 8);
            bf16x8 ah[4];
            #pragma unroll
            for (int rt = 0; rt < 4; ++rt)
                ah[rt] = *(const bf16x8*)&a_hi[rt * 16 + l16][kk * 32 + quad * 8];
            #pragma unroll
            for (int rt = 0; rt < 4; ++rt) {
                acc[rt][0] = __builtin_amdgcn_mfma_f32_16x16x32_bf16(ah[rt], b0, acc[rt][0], 0, 0, 0);
                acc[rt][1] = __builtin_amdgcn_mfma_f32_16x16x32_bf16(ah[rt], b1, acc[rt][1], 0, 0, 0);
            }
            if (fg) {
                const bf16x8 c0 = *(const bf16x8*)(wt_lo + (((size_t)(ng0 * 16 + kh)) * 64 + lane) * 8);
                const bf16x8 c1 = *(const bf16x8*)(wt_lo + (((size_t)((ng0 + 1) * 16 + kh)) * 64 + lane) * 8);
                bf16x8 al[4];
                #pragma unroll
                for (int rt = 0; rt < 4; ++rt)
                    al[rt] = *(const bf16x8*)&a_lo[rt * 16 + l16][kk * 32 + quad * 8];
                #pragma unroll
                for (int rt = 0; rt < 4; ++rt) {
                    acc[rt][0] = __builtin_amdgcn_mfma_f32_16x16x32_bf16(ah[rt], c0, acc[rt][0], 0, 0, 0);
                    acc[rt][0] = __builtin_amdgcn_mfma_f32_16x16x32_bf16(al[rt], b0, acc[rt][0], 0, 0, 0);
                    acc[rt][1] = __builtin_amdgcn_mfma_f32_16x16x32_bf16(ah[rt], c1, acc[rt][1], 0, 0, 0);
                    acc[rt][1] = __builtin_amdgcn_mfma_f32_16x16x32_bf16(al[rt], b1, acc[rt][1], 0, 0, 0);
                }
            }
        }
    }

    // ---- epilogue: bias + relu + bf16, route by wt column ----
    #pragma unroll
    for (int rt = 0; rt < 4; ++rt) {
        #pragma unroll
        for (int c = 0; c < 2; ++c) {
            const int wtc  = cbase + w * 32 + c * 16 + l16;   // 0..639
            const int rowl = rt * 16 + quad * 4;
            const float bias = fg ? (wtc < 64 ? bf[wtc] : bg[wtc - 64]) : bh[wtc - 128];
            const floatx4 v = acc[rt][c];
            if (fg) {
                unsigned short* dst = (wtc < 64) ? (f_bf + wtc) : (g_bf + wtc - 64);
                #pragma unroll
                for (int r = 0; r < 4; ++r) {
                    const float z = v[r] + bias;
                    dst[(size_t)(R0 + rowl + r) * C_DIM] = f2bf(z > 0.f ? z : 0.f);
                }
            } else {
                const int hc   = wtc - 128;                   // global F col
                const int grow = R0 + rowl;
                const int b    = grow >> 12, rl = grow & 4095;
                const int T    = rl >> 6, mloc = rl & 63;
                const int kh2  = mloc >> 5, q2 = (mloc >> 3) & 3, j0 = mloc & 7;
                ushortx4 st;
                #pragma unroll
                for (int r = 0; r < 4; ++r) {
                    const float z = v[r] + bias;
                    st[r] = f2bf(z > 0.f ? z : 0.f);
                }
                const size_t off = ((((size_t)(b * 64 + T) * 64) + (hc >> 4) * 2 + kh2) * 64
                                    + q2 * 16 + (hc & 15)) * 8 + j0;
                *(ushortx4*)(h_sw + off) = st;
            }
        }
    }
}

// ---------------------------------------------------------------------------
// Kernel 2: MFMA attention, fully fused, column-split. Round-4 post-mortem:
// the kernel is LDS-READ-BANDWIDTH bound (320 KB ds_read per block-iter,
// ~4050 cyc/iter). PV A-fragment traffic = P-bytes x (512/F_wave); round 4
// had F_wave=16 -> 4 GB. This round: F_wave=32 via PV ROW-SPLIT.
//
// QT=128, KT=64, 1024 threads (16 waves), grid = 4 b x 32 q-tiles x 2
// column-halves = 256 blocks. Score partition unchanged: wave w -> rows
// (w&7)*16, cols (w>>3)*32 of the 128x64 score tile.
// PV partition NEW: wave w -> row-half rh=w>>3 (64 rows) x 32 F-cols
// (cw=w&7): A-loads halve to 8 KB/wave/iter (A-frags reused across the 2
// col-groups in registers) -> PV LDS 256->128 KB/iter. The rh-twin waves
// load the same 4 KB h chunk; the 32 KB/iter h tile fits L1 -> re-read is
// cache-hot, no new HBM/L2 stream.
//
// LDS: exact 128 B stride + T2 XOR-swizzle (byte ^= (row&7)<<4), verified
// 0-conflict. Barriers lgkm-only. XCD map: XCD = b*2+ch.
// ---------------------------------------------------------------------------
#define QT 128
#define KT 64

__global__ __launch_bounds__(1024, 4) void attn_mfma_kernel(
    const unsigned short* __restrict__ f_bf, const unsigned short* __restrict__ g_bf,
    const unsigned short* __restrict__ h_sw, const float* __restrict__ gamma,
    const float* __restrict__ V, float* __restrict__ out)
{
    __shared__ __align__(16) unsigned short p_lds[2][QT * 64];   // 32 KB, swizzled
    __shared__ __align__(16) unsigned short g_lds[2][KT * 64];   // 16 KB, swizzled
    __shared__ float l_red[2][QT];
    __shared__ float l_inv[QT];

    const int t = threadIdx.x;
    const int w = t >> 6, lane = t & 63, quad = lane >> 4, l16 = lane & 15;
    const int sr = (w & 7) * 16, sc = (w >> 3) * 32;   // score stripe
    const int rh = w >> 3, cw = w & 7;                 // PV: rows rh*64, cols cw*32

    // bid&7 = XCD = b*2 + ch; bid>>3 = q-tile. Each XCD's 32 blocks share
    // one batch's g (512 KB) and one 2 MB h column-half -> L2-resident.
    const int bid = blockIdx.x;
    const int b   = (bid & 7) >> 1;
    const int ch  = bid & 1;
    const int qb  = bid >> 3;
    const int R0  = qb * QT;

    const unsigned short* fb    = f_bf + ((size_t)b * 4096 + R0) * C_DIM;
    const unsigned short* gb    = g_bf + (size_t)b * 4096 * C_DIM;
    const unsigned short* hbase = h_sw + (size_t)b * 64 * 32768;
    const int hgrp = ch * 32 + cw * 4;   // wave's 4 h groups (cols ch*256+cw*32..+32)

    bf16x8 f0, f1;
    {
        const unsigned short* fr = fb + (size_t)(sr + l16) * C_DIM + quad * 8;
        f0 = *(const bf16x8*)fr;
        f1 = *(const bf16x8*)(fr + 32);
    }
    float gam[2];
    gam[0] = gamma[ch * 256 + cw * 32 + l16];
    gam[1] = gamma[ch * 256 + cw * 32 + 16 + l16];

    floatx4 acc[4][2];   // [row-tile 0..3 within rh-half][col-16-group]
    #pragma unroll
    for (int rt = 0; rt < 4; ++rt)
        #pragma unroll
        for (int c = 0; c < 2; ++c)
            acc[rt][c] = (floatx4){0.f, 0.f, 0.f, 0.f};
    float run_l[4] = {0.f, 0.f, 0.f, 0.f};

    // cooperative g stage: thread t -> (row=t>>4, 8 B chunk), swizzled dest
    const int grow    = t >> 4, gk = (t & 15) * 4;           // shorts
    const int g_swoff = grow * 128 + ((gk * 2) ^ ((grow & 7) << 4));
    ushortx4 greg = *(const ushortx4*)(gb + (size_t)grow * C_DIM + gk);

    // loop-invariant swizzled score-read offsets (2 ct groups)
    const int sgrow0  = sc + l16;
    const int sgrow1  = sc + 16 + l16;
    const int sg0_off0 = sgrow0 * 128 + ((quad * 16)      ^ ((sgrow0 & 7) << 4));
    const int sg0_off1 = sgrow0 * 128 + ((quad * 16 + 64) ^ ((sgrow0 & 7) << 4));
    const int sg1_off0 = sgrow1 * 128 + ((quad * 16)      ^ ((sgrow1 & 7) << 4));
    const int sg1_off1 = sgrow1 * 128 + ((quad * 16 + 64) ^ ((sgrow1 & 7) << 4));

    for (int it = 0; it < 64; ++it) {
        const int buf = it & 1;
        const unsigned short* ht = hbase + (size_t)it * 32768 + (size_t)hgrp * 512;

        // ---- h prefetch: wave's contiguous 4 KB (groups hgrp..hgrp+3) ----
        // (rh-twin waves load the same chunk; 32 KB/iter tile is L1-hot)
        const bf16x8 h0 = *(const bf16x8*)(ht + (size_t)lane * 8);
        const bf16x8 h1 = *(const bf16x8*)(ht + 512 + (size_t)lane * 8);
        const bf16x8 h2 = *(const bf16x8*)(ht + 1024 + (size_t)lane * 8);
        const bf16x8 h3 = *(const bf16x8*)(ht + 1536 + (size_t)lane * 8);

        *(ushortx4*)((unsigned char*)&g_lds[buf][0] + g_swoff) = greg;
        if (it < 63)
            greg = *(const ushortx4*)(gb + (size_t)((it + 1) * KT + grow) * C_DIM + gk);
        lgkm_barrier();   // g[buf] visible

        const unsigned char* gB = (const unsigned char*)&g_lds[buf][0];
        unsigned char*       pB = (unsigned char*)&p_lds[buf][0];

        // ---- scores stripe: rows sr..sr+16, cols sc..sc+32 ----
        {
            const bf16x8 ga0 = *(const bf16x8*)(gB + sg0_off0);
            const bf16x8 ga1 = *(const bf16x8*)(gB + sg0_off1);
            floatx4 cc = (floatx4){0.f, 0.f, 0.f, 0.f};
            cc = __builtin_amdgcn_mfma_f32_16x16x32_bf16(f0, ga0, cc, 0, 0, 0);
            cc = __builtin_amdgcn_mfma_f32_16x16x32_bf16(f1, ga1, cc, 0, 0, 0);
            const bf16x8 gb0 = *(const bf16x8*)(gB + sg1_off0);
            const bf16x8 gb1 = *(const bf16x8*)(gB + sg1_off1);
            floatx4 cd = (floatx4){0.f, 0.f, 0.f, 0.f};
            cd = __builtin_amdgcn_mfma_f32_16x16x32_bf16(f0, gb0, cd, 0, 0, 0);
            cd = __builtin_amdgcn_mfma_f32_16x16x32_bf16(f1, gb1, cd, 0, 0, 0);
            #pragma unroll
            for (int r = 0; r < 4; ++r) {
                const int prow = sr + quad * 4 + r;
                const int swp  = (prow & 7) << 4;
                const float p0 = __expf(cc[r] - 32.f);
                const float p1 = __expf(cd[r] - 32.f);
                run_l[r] += p0 + p1;
                *(unsigned short*)(pB + prow * 128 + (((sc + l16) * 2)      ^ swp)) = f2bf(p0);
                *(unsigned short*)(pB + prow * 128 + (((sc + 16 + l16) * 2) ^ swp)) = f2bf(p1);
            }
        }
        lgkm_barrier();   // p[buf] visible

        // ---- PV: rows rh*64..+64 x wave's 32 cols; A-frags reused ----
        #pragma unroll
        for (int rt = 0; rt < 4; ++rt) {
            const int prow = rh * 64 + rt * 16 + l16;
            const int sw   = (prow & 7) << 4;
            const bf16x8 pf0 = *(const bf16x8*)(pB + prow * 128 + ((quad * 16)      ^ sw));
            const bf16x8 pf1 = *(const bf16x8*)(pB + prow * 128 + ((quad * 16 + 64) ^ sw));
            acc[rt][0] = __builtin_amdgcn_mfma_f32_16x16x32_bf16(pf0, h0, acc[rt][0], 0, 0, 0);
            acc[rt][0] = __builtin_amdgcn_mfma_f32_16x16x32_bf16(pf1, h1, acc[rt][0], 0, 0, 0);
            acc[rt][1] = __builtin_amdgcn_mfma_f32_16x16x32_bf16(pf0, h2, acc[rt][1], 0, 0, 0);
            acc[rt][1] = __builtin_amdgcn_mfma_f32_16x16x32_bf16(pf1, h3, acc[rt][1], 0, 0, 0);
        }
    }

    // ---- full row-sum l: shfl over l16, then LDS-sum across the 2 sc ----
    #pragma unroll
    for (int r = 0; r < 4; ++r) {
        float v = run_l[r];
        v += __shfl_xor(v, 1, 64);
        v += __shfl_xor(v, 2, 64);
        v += __shfl_xor(v, 4, 64);
        v += __shfl_xor(v, 8, 64);
        if (l16 == 0) l_red[w >> 3][sr + quad * 4 + r] = v;
    }
    __syncthreads();
    if (t < QT)
        l_inv[t] = 1.f / (l_red[0][t] + l_red[1][t]);
    __syncthreads();

    // ---- fused epilogue: out = gamma * O/l + V (fp32, final) ----
    const float* Vb = V   + ((size_t)b * 4096 + R0) * F_DIM;
    float*       ob = out + ((size_t)b * 4096 + R0) * F_DIM;
    #pragma unroll
    for (int rt = 0; rt < 4; ++rt) {
        #pragma unroll
        for (int r = 0; r < 4; ++r) {
            const int row = rh * 64 + rt * 16 + quad * 4 + r;
            const float li = l_inv[row];
            #pragma unroll
            for (int c = 0; c < 2; ++c) {
                const int col = ch * 256 + cw * 32 + c * 16 + l16;
                ob[(size_t)row * F_DIM + col] =
                    gam[c] * acc[rt][c][r] * li + Vb[(size_t)row * F_DIM + col];
            }
        }
    }
}

// ---------------------------------------------------------------------------
extern "C" void kernel_launch(void* const* d_in, const int* in_sizes, int n_in,
                              void* d_out, int out_size, void* d_ws, size_t ws_size,
                              hipStream_t stream) {
    const float* V     = (const float*)d_in[0];
    const float* Wf    = (const float*)d_in[1];
    const float* bf    = (const float*)d_in[2];
    const float* Wg    = (const float*)d_in[3];
    const float* bg    = (const float*)d_in[4];
    const float* Wh    = (const float*)d_in[5];
    const float* bh    = (const float*)d_in[6];
    const float* gamma = (const float*)d_in[7];
    float* out = (float*)d_out;

    // ws: f 2MB | g 2MB | h_sw 16MB | wt_hi 0.64 | wt_lo 0.64
    unsigned short* f_bf  = (unsigned short*)d_ws;
    unsigned short* g_bf  = f_bf + (size_t)M_ROWS * C_DIM;
    unsigned short* h_sw  = g_bf + (size_t)M_ROWS * C_DIM;
    unsigned short* wt_hi = h_sw + (size_t)4 * F_DIM * 4096;
    unsigned short* wt_lo = wt_hi + (size_t)640 * F_DIM;

    prep_w_kernel<<<640, 64, 0, stream>>>(Wf, Wg, Wh, wt_hi, wt_lo);
    embed_mfma_kernel<<<1280, 256, 0, stream>>>(
        V, wt_hi, wt_lo, bf, bg, bh, f_bf, g_bf, h_sw);
    attn_mfma_kernel<<<256, 1024, 0, stream>>>(f_bf, g_bf, h_sw, gamma, V, out);
}